// Round 1
// baseline (251.587 us; speedup 1.0000x reference)
//
#include <hip/hip_runtime.h>
#include <hip/hip_bf16.h>

typedef __attribute__((ext_vector_type(8))) short short8;
typedef __attribute__((ext_vector_type(4))) short short4v;
typedef __attribute__((ext_vector_type(4))) float f32x4;

#define S_LEN 2048
#define D_DIM 64
#define QT 128
#define KT 64
#define LDK 72

static __device__ __forceinline__ short f2bf(float f) {
  union { float f; unsigned u; } c; c.f = f;
  unsigned u = c.u;
  return (short)((u + 0x7fffu + ((u >> 16) & 1u)) >> 16);
}

__global__ __launch_bounds__(256, 2)
void attn_fwd(const float* __restrict__ Qg, const float* __restrict__ Kg,
              const float* __restrict__ Vg, const float* __restrict__ sp,
              float* __restrict__ Og)
{
  __shared__ short Kl[KT * LDK];        // K tile [kv][d], bf16
  __shared__ short Vt[D_DIM * LDK];     // V tile transposed [d][kv], bf16
  __shared__ short Pl[4 * 32 * LDK];    // per-wave P tile [q][kv], bf16

  const int tid = threadIdx.x;
  const int w = tid >> 6;     // wave id 0..3
  const int l = tid & 63;     // lane
  const int m = l & 15;
  const int g = l >> 4;
  const int bh = blockIdx.y;
  const int qb = blockIdx.x * QT;
  const float scale = *sp;

  const float* Qh = Qg + (size_t)bh * S_LEN * D_DIM;
  const float* Kh = Kg + (size_t)bh * S_LEN * D_DIM;
  const float* Vh = Vg + (size_t)bh * S_LEN * D_DIM;
  float*       Oh = Og + (size_t)bh * S_LEN * D_DIM;

  // ---- Q A-frags (scale folded in), kept in registers ----
  // A layout (16x16x32): row = lane&15, k = (lane>>4)*8 + j
  short8 aQ[2][2];
#pragma unroll
  for (int rb = 0; rb < 2; ++rb)
#pragma unroll
    for (int kb = 0; kb < 2; ++kb) {
      const float* src = Qh + (size_t)(qb + w * 32 + rb * 16 + m) * D_DIM + kb * 32 + g * 8;
      float4 f0 = *(const float4*)src;
      float4 f1 = *(const float4*)(src + 4);
      short8 a;
      a[0] = f2bf(f0.x * scale); a[1] = f2bf(f0.y * scale);
      a[2] = f2bf(f0.z * scale); a[3] = f2bf(f0.w * scale);
      a[4] = f2bf(f1.x * scale); a[5] = f2bf(f1.y * scale);
      a[6] = f2bf(f1.z * scale); a[7] = f2bf(f1.w * scale);
      aQ[rb][kb] = a;
    }

  // ---- accumulators / softmax state ----
  f32x4 o[2][4];
  float mr[2][4], lr[2][4];
#pragma unroll
  for (int rb = 0; rb < 2; ++rb)
#pragma unroll
    for (int r = 0; r < 4; ++r) {
      mr[rb][r] = -INFINITY; lr[rb][r] = 0.f;
#pragma unroll
      for (int db = 0; db < 4; ++db) o[rb][db][r] = 0.f;
    }

  for (int kv0 = 0; kv0 < S_LEN; kv0 += KT) {
    // ---- stage K tile -> Kl[kv][d] (coalesced read, b64 LDS write) ----
#pragma unroll
    for (int it = 0; it < 4; ++it) {
      int row = (tid >> 4) + 16 * it;
      int c4  = (tid & 15) * 4;
      float4 f = *(const float4*)(Kh + (size_t)(kv0 + row) * D_DIM + c4);
      short4v s; s[0] = f2bf(f.x); s[1] = f2bf(f.y); s[2] = f2bf(f.z); s[3] = f2bf(f.w);
      *(short4v*)&Kl[row * LDK + c4] = s;
    }
    // ---- stage V^T -> Vt[d][kv] (lane owns row d=l; coalesced global reads) ----
#pragma unroll
    for (int it = 0; it < 4; ++it) {
      int kvb = w * 4 + 16 * it;
      short4v s;
#pragma unroll
      for (int i = 0; i < 4; ++i)
        s[i] = f2bf(Vh[(size_t)(kv0 + kvb + i) * D_DIM + l]);
      *(short4v*)&Vt[l * LDK + kvb] = s;
    }
    __syncthreads();

    // ---- scores: S = (Q*scale) @ K^T, 16x16x32 MFMA ----
    f32x4 sc[2][4];
#pragma unroll
    for (int rb = 0; rb < 2; ++rb)
#pragma unroll
      for (int cb = 0; cb < 4; ++cb)
#pragma unroll
        for (int r = 0; r < 4; ++r) sc[rb][cb][r] = 0.f;

#pragma unroll
    for (int cb = 0; cb < 4; ++cb) {
#pragma unroll
      for (int kb = 0; kb < 2; ++kb) {
        // B layout: col(kv) = lane&15, k(d) = (lane>>4)*8 + j  -> contiguous along d
        short8 bK = *(const short8*)&Kl[(cb * 16 + m) * LDK + kb * 32 + g * 8];
#pragma unroll
        for (int rb = 0; rb < 2; ++rb)
          sc[rb][cb] = __builtin_amdgcn_mfma_f32_16x16x32_bf16(aQ[rb][kb], bK, sc[rb][cb], 0, 0, 0);
      }
    }

    // ---- online softmax (C layout: col = lane&15, row = 4*(lane>>4)+r) ----
    float fac[2][4];
#pragma unroll
    for (int rb = 0; rb < 2; ++rb)
#pragma unroll
      for (int r = 0; r < 4; ++r) {
        float tm = fmaxf(fmaxf(sc[rb][0][r], sc[rb][1][r]), fmaxf(sc[rb][2][r], sc[rb][3][r]));
#pragma unroll
        for (int off = 1; off <= 8; off <<= 1)
          tm = fmaxf(tm, __shfl_xor(tm, off, 64));
        float mn = fmaxf(mr[rb][r], tm);
        fac[rb][r] = __expf(mr[rb][r] - mn);   // exp(-inf)=0 on first tile
        mr[rb][r] = mn;
      }
#pragma unroll
    for (int rb = 0; rb < 2; ++rb) {
#pragma unroll
      for (int cb = 0; cb < 4; ++cb)
#pragma unroll
        for (int r = 0; r < 4; ++r)
          sc[rb][cb][r] = __expf(sc[rb][cb][r] - mr[rb][r]);
#pragma unroll
      for (int r = 0; r < 4; ++r) {
        float ps = sc[rb][0][r] + sc[rb][1][r] + sc[rb][2][r] + sc[rb][3][r];
#pragma unroll
        for (int off = 1; off <= 8; off <<= 1)
          ps += __shfl_xor(ps, off, 64);
        lr[rb][r] = lr[rb][r] * fac[rb][r] + ps;
      }
    }

    // ---- rescale O, spill P (bf16) to per-wave LDS ----
#pragma unroll
    for (int rb = 0; rb < 2; ++rb) {
#pragma unroll
      for (int db = 0; db < 4; ++db)
#pragma unroll
        for (int r = 0; r < 4; ++r)
          o[rb][db][r] *= fac[rb][r];
#pragma unroll
      for (int cb = 0; cb < 4; ++cb)
#pragma unroll
        for (int r = 0; r < 4; ++r)
          Pl[(w * 32 + rb * 16 + g * 4 + r) * LDK + cb * 16 + m] = f2bf(sc[rb][cb][r]);
    }

    // ---- PV: O += P @ V (A from Pl, B from Vt; same-wave DS is in-order) ----
    short8 aP[2][2];
#pragma unroll
    for (int rb = 0; rb < 2; ++rb)
#pragma unroll
      for (int ka = 0; ka < 2; ++ka)
        aP[rb][ka] = *(const short8*)&Pl[(w * 32 + rb * 16 + m) * LDK + ka * 32 + g * 8];
#pragma unroll
    for (int db = 0; db < 4; ++db) {
#pragma unroll
      for (int ka = 0; ka < 2; ++ka) {
        short8 bV = *(const short8*)&Vt[(db * 16 + m) * LDK + ka * 32 + g * 8];
#pragma unroll
        for (int rb = 0; rb < 2; ++rb)
          o[rb][db] = __builtin_amdgcn_mfma_f32_16x16x32_bf16(aP[rb][ka], bV, o[rb][db], 0, 0, 0);
      }
    }
    __syncthreads();
  }

  // ---- epilogue: O = acc / l ----
#pragma unroll
  for (int rb = 0; rb < 2; ++rb)
#pragma unroll
    for (int db = 0; db < 4; ++db)
#pragma unroll
      for (int r = 0; r < 4; ++r) {
        int q = qb + w * 32 + rb * 16 + g * 4 + r;
        Oh[(size_t)q * D_DIM + db * 16 + m] = o[rb][db][r] / lr[rb][r];
      }
}

extern "C" void kernel_launch(void* const* d_in, const int* in_sizes, int n_in,
                              void* d_out, int out_size, void* d_ws, size_t ws_size,
                              hipStream_t stream) {
  (void)in_sizes; (void)n_in; (void)d_ws; (void)ws_size; (void)out_size;
  const float* Q  = (const float*)d_in[0];
  const float* K  = (const float*)d_in[1];
  const float* V  = (const float*)d_in[2];
  const float* sp = (const float*)d_in[3];
  float* O = (float*)d_out;
  dim3 grid(S_LEN / QT, 64);
  attn_fwd<<<grid, 256, 0, stream>>>(Q, K, V, sp, O);
}

// Round 3
// 131.756 us; speedup vs baseline: 1.9095x; 1.9095x over previous
//
#include <hip/hip_runtime.h>
#include <hip/hip_bf16.h>

typedef __attribute__((ext_vector_type(8))) short short8;
typedef __attribute__((ext_vector_type(16))) float f32x16;
typedef __attribute__((ext_vector_type(2))) unsigned uint2v;

#define S_LEN 2048
#define D_DIM 64
#define QT 128
#define KT 64

static __device__ __forceinline__ unsigned cvt_pk(float lo, float hi) {
  unsigned r;
  asm("v_cvt_pk_bf16_f32 %0, %1, %2" : "=v"(r) : "v"(lo), "v"(hi));
  return r;
}

// v_permlane32_swap_b32 vdst, vsrc: vdst.lanes[32:63] <-> vsrc.lanes[0:31]
// i.e. new vdst = {vdst.lo, vsrc.lo}, new vsrc = {vdst.hi, vsrc.hi}
static __device__ __forceinline__ void plswap(unsigned &vdst, unsigned &vsrc) {
  uint2v r = __builtin_amdgcn_permlane32_swap(vdst, vsrc, false, false);
  vdst = r.x; vsrc = r.y;
}

union U8 { unsigned u[4]; short8 s; };

__global__ __launch_bounds__(256, 4)
void attn_fwd(const float* __restrict__ Qg, const float* __restrict__ Kg,
              const float* __restrict__ Vg, const float* __restrict__ sp,
              float* __restrict__ Og)
{
  // LDS: Kl [64][64] bf16 swizzled (8192B) | Vt [64][64] bf16 (d-major) swizzled (8192B)
  // epilogue: Ow 4 waves x [32][68] f32 (34816B), overlapping
  __shared__ __align__(16) unsigned char smem[34816];
  short* Kl = (short*)smem;
  short* Vt = (short*)(smem + 8192);

  const int tid = threadIdx.x;
  const int w   = tid >> 6;
  const int l   = tid & 63;
  const int q32 = l & 31;
  const int hi  = l >> 5;
  const int bh  = blockIdx.y;
  const int qb  = blockIdx.x * QT;

  const float* Qh = Qg + (size_t)bh * (S_LEN * D_DIM);
  const float* Kh = Kg + (size_t)bh * (S_LEN * D_DIM);
  const float* Vh = Vg + (size_t)bh * (S_LEN * D_DIM);
  float*       Oh = Og + (size_t)bh * (S_LEN * D_DIM);

  const float qscale = sp[0] * 1.4426950408889634f;  // fold scale*log2(e) into Q

  // ---- Q fragments in registers: B-layout, lane holds Q[q32][dk*16 + hi*8 + j] ----
  short8 qf[4];
  {
    const float* qrow = Qh + (size_t)(qb + w * 32 + q32) * D_DIM + hi * 8;
#pragma unroll
    for (int dk = 0; dk < 4; ++dk) {
      float4 f0 = *(const float4*)(qrow + dk * 16);
      float4 f1 = *(const float4*)(qrow + dk * 16 + 4);
      U8 u;
      u.u[0] = cvt_pk(f0.x * qscale, f0.y * qscale);
      u.u[1] = cvt_pk(f0.z * qscale, f0.w * qscale);
      u.u[2] = cvt_pk(f1.x * qscale, f1.y * qscale);
      u.u[3] = cvt_pk(f1.z * qscale, f1.w * qscale);
      qf[dk] = u.s;
    }
  }

  f32x16 o0, o1;
#pragma unroll
  for (int r = 0; r < 16; ++r) { o0[r] = 0.f; o1[r] = 0.f; }
  float m_run = -INFINITY, l_run = 0.f;

  // staging maps
  const int krow = tid >> 2, kcol = (tid & 3) * 16;   // K: 16 floats/thread
  const int vd   = (tid & 15) * 4, vk = (tid >> 4) * 4; // V: 4x4 transpose block
  char* kdst0 = (char*)Kl + ((krow << 7) + ((kcol * 2)      ^ ((krow & 7) << 4)));
  char* kdst1 = (char*)Kl + ((krow << 7) + ((kcol * 2 + 16) ^ ((krow & 7) << 4)));

  const char* kb  = (const char*)Kl + (q32 << 7);
  const char* vb  = (const char*)Vt + (q32 << 7);
  const int   swz = (q32 & 7) << 4;

  for (int kv0 = 0; kv0 < S_LEN; kv0 += KT) {
    __syncthreads();
    // ---- stage K tile -> Kl[kv][d] (bf16, swizzled) ----
    {
      const float* src = Kh + (size_t)(kv0 + krow) * D_DIM + kcol;
      float4 a = ((const float4*)src)[0];
      float4 b = ((const float4*)src)[1];
      float4 c = ((const float4*)src)[2];
      float4 d = ((const float4*)src)[3];
      *(uint4*)kdst0 = make_uint4(cvt_pk(a.x, a.y), cvt_pk(a.z, a.w),
                                  cvt_pk(b.x, b.y), cvt_pk(b.z, b.w));
      *(uint4*)kdst1 = make_uint4(cvt_pk(c.x, c.y), cvt_pk(c.z, c.w),
                                  cvt_pk(d.x, d.y), cvt_pk(d.z, d.w));
    }
    // ---- stage V^T -> Vt[d][kv] (bf16, swizzled) via 4x4 register transpose ----
    {
      const float* src = Vh + (size_t)(kv0 + vk) * D_DIM + vd;
      float4 r0 = *(const float4*)(src);
      float4 r1 = *(const float4*)(src + D_DIM);
      float4 r2 = *(const float4*)(src + 2 * D_DIM);
      float4 r3 = *(const float4*)(src + 3 * D_DIM);
#define VSTORE(c, e0, e1, e2, e3)                                              \
      { unsigned lo = cvt_pk(e0, e1); unsigned hh = cvt_pk(e2, e3);            \
        char* p = (char*)Vt + (((vd + c) << 7) +                               \
                   ((vk * 2) ^ (((vd + c) & 7) << 4)));                        \
        *(unsigned long long*)p = ((unsigned long long)hh << 32) | (unsigned long long)lo; }
      VSTORE(0, r0.x, r1.x, r2.x, r3.x)
      VSTORE(1, r0.y, r1.y, r2.y, r3.y)
      VSTORE(2, r0.z, r1.z, r2.z, r3.z)
      VSTORE(3, r0.w, r1.w, r2.w, r3.w)
#undef VSTORE
    }
    __syncthreads();

    // ---- QK^T swapped: st = S^T[kv][q], lane owns column q=q32 ----
    f32x16 st0, st1;
#pragma unroll
    for (int r = 0; r < 16; ++r) { st0[r] = 0.f; st1[r] = 0.f; }
    __builtin_amdgcn_s_setprio(1);
#pragma unroll
    for (int dk = 0; dk < 4; ++dk) {
      short8 ka = *(const short8*)(kb + ((dk * 32 + hi * 16) ^ swz));
      st0 = __builtin_amdgcn_mfma_f32_32x32x16_bf16(ka, qf[dk], st0, 0, 0, 0);
    }
#pragma unroll
    for (int dk = 0; dk < 4; ++dk) {
      short8 ka = *(const short8*)(kb + 32 * 128 + ((dk * 32 + hi * 16) ^ swz));
      st1 = __builtin_amdgcn_mfma_f32_32x32x16_bf16(ka, qf[dk], st1, 0, 0, 0);
    }
    __builtin_amdgcn_s_setprio(0);

    // ---- online softmax, fully per-lane (log2 domain) ----
    float tm = fmaxf(st0[0], st1[0]);
#pragma unroll
    for (int r = 1; r < 16; ++r) tm = fmaxf(tm, fmaxf(st0[r], st1[r]));
    tm = fmaxf(tm, __shfl_xor(tm, 32, 64));
    float mn  = fmaxf(m_run, tm);
    float fac = __builtin_amdgcn_exp2f(m_run - mn);
    m_run = mn;
    float s0 = 0.f, s1 = 0.f, s2 = 0.f, s3 = 0.f;
#pragma unroll
    for (int r = 0; r < 16; ++r) {
      st0[r] = __builtin_amdgcn_exp2f(st0[r] - mn);
      st1[r] = __builtin_amdgcn_exp2f(st1[r] - mn);
      if ((r & 3) == 0) { s0 += st0[r]; s0 += st1[r]; }
      else if ((r & 3) == 1) { s1 += st0[r]; s1 += st1[r]; }
      else if ((r & 3) == 2) { s2 += st0[r]; s2 += st1[r]; }
      else { s3 += st0[r]; s3 += st1[r]; }
    }
    float ps = (s0 + s1) + (s2 + s3);
    ps += __shfl_xor(ps, 32, 64);
    l_run = l_run * fac + ps;
#pragma unroll
    for (int r = 0; r < 16; ++r) { o0[r] *= fac; o1[r] *= fac; }

    // ---- PV: O^T[d][q] += V^T-frag (A) x P^T-frag (B), per 32-kv subblock ----
    // P^T B-frag assembly: lane (hi) needs kv = ks*16 + 8*hi + j.
    // plswap(pk0,pk2): new pk0 = {hi0:kv(0,1) | hi1:kv(8,9)}  = u[0]
    //                  new pk2 = {hi0:kv(4,5) | hi1:kv(12,13)} = u[2]
#pragma unroll
    for (int sb = 0; sb < 2; ++sb) {
      f32x16& st = sb ? st1 : st0;
      unsigned pk[8];
#pragma unroll
      for (int j = 0; j < 8; ++j) pk[j] = cvt_pk(st[2 * j], st[2 * j + 1]);
      plswap(pk[0], pk[2]);
      plswap(pk[1], pk[3]);
      plswap(pk[4], pk[6]);
      plswap(pk[5], pk[7]);
      U8 f0, f1;
      f0.u[0] = pk[0]; f0.u[1] = pk[1]; f0.u[2] = pk[2]; f0.u[3] = pk[3];
      f1.u[0] = pk[4]; f1.u[1] = pk[5]; f1.u[2] = pk[6]; f1.u[3] = pk[7];
      __builtin_amdgcn_s_setprio(1);
#pragma unroll
      for (int nb = 0; nb < 2; ++nb) {
        const char* vbn = vb + nb * 32 * 128;
        short8 va0 = *(const short8*)(vbn + ((sb * 64 + 0  + hi * 16) ^ swz));
        short8 va1 = *(const short8*)(vbn + ((sb * 64 + 32 + hi * 16) ^ swz));
        f32x16& oo = nb ? o1 : o0;
        oo = __builtin_amdgcn_mfma_f32_32x32x16_bf16(va0, f0.s, oo, 0, 0, 0);
        oo = __builtin_amdgcn_mfma_f32_32x32x16_bf16(va1, f1.s, oo, 0, 0, 0);
      }
      __builtin_amdgcn_s_setprio(0);
    }
  }

  // ---- epilogue: divide by l, transpose through LDS, coalesced store ----
  __syncthreads();  // Kl/Vt dead
  float* Ow = (float*)smem + w * (32 * 68);
  float rl = 1.0f / l_run;
#pragma unroll
  for (int nb = 0; nb < 2; ++nb)
#pragma unroll
    for (int rr = 0; rr < 4; ++rr) {
      float4 v;
      if (nb == 0) { v.x = o0[rr*4+0]*rl; v.y = o0[rr*4+1]*rl; v.z = o0[rr*4+2]*rl; v.w = o0[rr*4+3]*rl; }
      else         { v.x = o1[rr*4+0]*rl; v.y = o1[rr*4+1]*rl; v.z = o1[rr*4+2]*rl; v.w = o1[rr*4+3]*rl; }
      *(float4*)&Ow[q32 * 68 + nb * 32 + rr * 8 + hi * 4] = v;
    }
#pragma unroll
  for (int i = 0; i < 8; ++i) {
    int e = i * 256 + l * 4;
    int row = e >> 6, col = e & 63;
    float4 v = *(const float4*)&Ow[row * 68 + col];
    *(float4*)(Oh + (size_t)(qb + w * 32 + row) * D_DIM + col) = v;
  }
}

extern "C" void kernel_launch(void* const* d_in, const int* in_sizes, int n_in,
                              void* d_out, int out_size, void* d_ws, size_t ws_size,
                              hipStream_t stream) {
  (void)in_sizes; (void)n_in; (void)d_ws; (void)ws_size; (void)out_size;
  const float* Q  = (const float*)d_in[0];
  const float* K  = (const float*)d_in[1];
  const float* V  = (const float*)d_in[2];
  const float* sp = (const float*)d_in[3];
  float* O = (float*)d_out;
  dim3 grid(S_LEN / QT, 64);
  attn_fwd<<<grid, 256, 0, stream>>>(Q, K, V, sp, O);
}